// Round 7
// baseline (97.748 us; speedup 1.0000x reference)
//
#include <hip/hip_runtime.h>
#include <hip/hip_bf16.h>
#include <math.h>

// Bilateral Gaussian filter: out[b,c,i] = sum_j exp(-0.5|f_i-f_j|^2) * cur[b,c,j]
// f = [y/8, x/8, r/.5, g/.5, b/.5] (D=5). B=2, C=21, N=9216.
//
// Round 12: 1-wave blocks.
//  R11 found the timed window = harness 256MiB ws-poison fill (41.6us,
//  untouchable) + prep (~6) + main (41.5). Main is residency-limited:
//  Occ 31% (~2.5 waves/SIMD) with 4-wave blocks, though HW allows 8
//  blocks/CU. Hypothesis: block-granularity scheduling is the limiter ->
//  split to 64-thread (1-wave) blocks; same 13824 waves (G=24) but each
//  independently schedulable, LDS 4.2KB/block, wave-slot cap 32/CU.
//  Also: P-pack via __float22bfloat162_rn (compiler v_cvt_pk_bf16_f32,
//  RNE; NOT the R6 hand-asm that broke) -- saves 32cyc/qstep.
//  Prep (2-node, zero-fold) byte-identical to R10/R11.

#define HH 96
#define WW 96
#define NN (HH * WW)   // 9216
#define NB 2
#define NC 21

typedef __attribute__((ext_vector_type(8))) short short8;
typedef __attribute__((ext_vector_type(16))) float f32x16;

constexpr float INV_TA = 0.125f;  // 1/theta_alpha
constexpr float INV_TB = 2.0f;    // 1/theta_beta
constexpr float LOG2E  = 1.44269504088896340736f;

constexpr int BLK   = 256;           // prep block size
constexpr int MBLK  = 64;            // main block size: 1 wave
constexpr int ITILE = 32;            // i per block (one 32-i subtile)
constexpr int NIT   = NN / ITILE;    // 288
constexpr int NJB   = NN / 32;       // 288 j-blocks
constexpr int G     = 24;            // j-groups
constexpr int QW    = NJB / G;       // 12 j-blocks per wave

// ws layout: V [b][jblk(288)][m(2)][h(2)][c(32)] x 16B, then F [b][half][j] x 16B
constexpr size_t VG_BYTES = (size_t)NB * NJB * 128 * 16;  // 1,179,648
constexpr size_t FJA_OFF  = VG_BYTES;                     // + NB*2*NN*16 = 589,824

constexpr int NVU = NB * NJB * 128;        // 73728 V-pack tasks
constexpr int NFT = NB * NN;               // 18432 feature tasks
constexpr int NZ  = NB * NC * NN / 4;      // 96768 float4 zero units
constexpr int PREP_TASKS = NVU + NFT + NZ; // 188928 = 738*256

#if defined(__has_builtin)
#if __has_builtin(__builtin_amdgcn_exp2f)
#define EXP2F(x) __builtin_amdgcn_exp2f(x)
#endif
#endif
#ifndef EXP2F
#define EXP2F(x) exp2f(x)
#endif

__device__ __forceinline__ unsigned short bf16_rne(float f) {
    __hip_bfloat16 h = __float2bfloat16(f);
    unsigned short u; __builtin_memcpy(&u, &h, 2); return u;
}
__device__ __forceinline__ float bf16_f(unsigned short u) {
    __hip_bfloat16 h; __builtin_memcpy(&h, &u, 2); return __bfloat162float(h);
}
// pack two fp32 -> dword of two bf16 (round-up-bias trick; prep only)
__device__ __forceinline__ unsigned pk2(float a, float b) {
    const unsigned u0 = __float_as_uint(a) + 0x8000u;
    const unsigned u1 = __float_as_uint(b) + 0x8000u;
    return __builtin_amdgcn_perm(u1, u0, 0x07060302u);  // low=a, high=b
}
// packed RNE fp32x2 -> bf16x2 via HIP intrinsic (compiler emits v_cvt_pk)
__device__ __forceinline__ unsigned pkrn(float a, float b) {
    __hip_bfloat162 h = __float22bfloat162_rn(float2{a, b});  // x=lo, y=hi
    unsigned u; __builtin_memcpy(&u, &h, 4); return u;
}

// ---------------- prep: pack V, F_j fragments, zero out ----------------
__global__ __launch_bounds__(BLK)
void prep_kernel(const float* __restrict__ cur, const float* __restrict__ img,
                 unsigned char* __restrict__ ws, float* __restrict__ out) {
    const int t = blockIdx.x * BLK + threadIdx.x;
    if (t < NVU) {
        // V unit: t = ((b*288+jblk)*4 + m*2 + h)*32 + c -> 8 bf16 = V[j(k)][c]
        const int c    = t & 31;
        const int h    = (t >> 5) & 1;
        const int m    = (t >> 6) & 1;
        const int jw   = t >> 7;          // b*288 + jblk
        const int b    = jw / NJB;
        const int jblk = jw % NJB;
        // k-slot s=8h+t' -> physical j offset = swap bits2,3 of s:
        //   t'=0..3 -> jb+t', t'=4..7 -> jb+8+(t'&3)
        const int jb = jblk * 32 + m * 16 + 4 * h;
        float4 qa = {0, 0, 0, 0}, qb = {0, 0, 0, 0};
        if (c < NC) {
            const float* row = cur + ((size_t)b * NC + c) * NN;
            qa = *(const float4*)(row + jb);
            qb = *(const float4*)(row + jb + 8);
        }
        uint4 o;
        o.x = pk2(qa.x, qa.y); o.y = pk2(qa.z, qa.w);
        o.z = pk2(qb.x, qb.y); o.w = pk2(qb.z, qb.w);
        *(uint4*)(ws + (size_t)t * 16) = o;
    } else if (t < NVU + NFT) {
        const int tf = t - NVU;
        const int b = tf / NN;
        const int j = tf % NN;
        const float y = (float)(j / WW) * INV_TA;   // exact in bf16
        const float x = (float)(j % WW) * INV_TA;   // exact in bf16
        const float* ib = img + (size_t)b * 3 * NN;
        unsigned short ch[3], cl[3]; float cf[3];
        #pragma unroll
        for (int d = 0; d < 3; ++d) {
            const float c = ib[d * NN + j] * INV_TB;
            ch[d] = bf16_rne(c);
            const float chf = bf16_f(ch[d]);
            cl[d] = bf16_rne(c - chf);
            cf[d] = chf + bf16_f(cl[d]);
        }
        const float e = -0.5f * (y * y + x * x +
                                 cf[0] * cf[0] + cf[1] * cf[1] + cf[2] * cf[2]);
        const unsigned short eh = bf16_rne(e);
        const unsigned short el = bf16_rne(e - bf16_f(eh));
        const unsigned short yb = bf16_rne(y), xb = bf16_rne(x);
        const unsigned short one = 0x3F80;
        unsigned short* u0 = (unsigned short*)
            (ws + FJA_OFF + ((size_t)(b * 2 + 0) * NN + j) * 16);
        unsigned short* u1 = (unsigned short*)
            (ws + FJA_OFF + ((size_t)(b * 2 + 1) * NN + j) * 16);
        // A-frag slots 0-7:  [y, x, ch0,ch1,ch2, cl0,cl1,cl2]
        u0[0] = yb; u0[1] = xb; u0[2] = ch[0]; u0[3] = ch[1]; u0[4] = ch[2];
        u0[5] = cl[0]; u0[6] = cl[1]; u0[7] = cl[2];
        // A-frag slots 8-15: [ch0,ch1,ch2, ejh, ejl, 1, 1, 0]
        u1[0] = ch[0]; u1[1] = ch[1]; u1[2] = ch[2]; u1[3] = eh; u1[4] = el;
        u1[5] = one; u1[6] = one; u1[7] = 0;
    } else {
        ((float4*)out)[t - NVU - NFT] = float4{0.0f, 0.0f, 0.0f, 0.0f};
    }
}

// ---------------- main kernel: 1-wave blocks, S-MFMA pipelined ----------------
__global__ __launch_bounds__(MBLK)
void perm_gauss_mfma(const float* __restrict__ img,
                     const unsigned char* __restrict__ ws,
                     float* __restrict__ out) {
    __shared__ __align__(16) float tile[32 * 33];   // per-wave epilogue tile
    const int lane = threadIdx.x & 63;
    const int il   = lane & 31;
    const int half = lane >> 5;

    const int it = blockIdx.x, g = blockIdx.y, b = blockIdx.z;
    const int ibase = it * ITILE;
    const float* imgb = img + (size_t)b * 3 * NN;
    float* outb = out + (size_t)b * NC * NN;

    // ---- B-operand fragment: F_i for my column i, my k-half ----
    const int ig = ibase + il;
    const float y = (float)(ig / WW) * INV_TA;
    const float x = (float)(ig % WW) * INV_TA;
    unsigned short ch[3], cl[3]; float cf[3];
    #pragma unroll
    for (int d = 0; d < 3; ++d) {
        const float c = imgb[d * NN + ig] * INV_TB;
        ch[d] = bf16_rne(c);
        const float chf = bf16_f(ch[d]);
        cl[d] = bf16_rne(c - chf);
        cf[d] = chf + bf16_f(cl[d]);
    }
    const float e = -0.5f * (y * y + x * x +
                             cf[0] * cf[0] + cf[1] * cf[1] + cf[2] * cf[2]);
    const unsigned short eh = bf16_rne(e);
    const unsigned short el = bf16_rne(e - bf16_f(eh));
    const unsigned short one = 0x3F80;
    union { unsigned short u[8]; short8 v; } bfi;
    if (half == 0) {
        // B slots 0-7: [y, x, ch0,ch1,ch2, ch0,ch1,ch2]
        bfi.u[0] = bf16_rne(y); bfi.u[1] = bf16_rne(x);
        bfi.u[2] = ch[0]; bfi.u[3] = ch[1]; bfi.u[4] = ch[2];
        bfi.u[5] = ch[0]; bfi.u[6] = ch[1]; bfi.u[7] = ch[2];
    } else {
        // B slots 8-15: [cl0,cl1,cl2, 1, 1, eih, eil, 0]
        bfi.u[0] = cl[0]; bfi.u[1] = cl[1]; bfi.u[2] = cl[2];
        bfi.u[3] = one; bfi.u[4] = one; bfi.u[5] = eh; bfi.u[6] = el;
        bfi.u[7] = 0;
    }

    f32x16 acc, zz;
    #pragma unroll
    for (int r = 0; r < 16; ++r) { acc[r] = 0.0f; zz[r] = 0.0f; }

    // ---- stream j-blocks directly from L2-resident ws ----
    const int jb0 = g * QW;
    const unsigned char* fp = ws + FJA_OFF +
        ((size_t)(b * 2 + half) * NN + (size_t)jb0 * 32 + il) * 16;
    const unsigned char* vp = ws +
        ((size_t)(b * NJB + jb0) * 128 + half * 32 + il) * 16;

    // exp/pack + PV for one j-block (consumes s, V1, V2)
    auto consume = [&](const f32x16& s, short8 V1, short8 V2) {
        float w[16];
        #pragma unroll
        for (int r = 0; r < 16; ++r) w[r] = EXP2F(s[r] * LOG2E);
        union { unsigned dw[4]; short8 v; } a1, a2;
        #pragma unroll
        for (int d = 0; d < 4; ++d) {
            a1.dw[d] = pkrn(w[2 * d],     w[2 * d + 1]);
            a2.dw[d] = pkrn(w[8 + 2 * d], w[9 + 2 * d]);
        }
        acc = __builtin_amdgcn_mfma_f32_32x32x16_bf16(a1.v, V1, acc, 0, 0, 0);
        acc = __builtin_amdgcn_mfma_f32_32x32x16_bf16(a2.v, V2, acc, 0, 0, 0);
    };

    // prologue: af for q=0,1; V for q=0; S for q=0 in flight
    short8 af0 = *(const short8*)fp;
    short8 af1 = *(const short8*)(fp + 512);
    short8 v1  = *(const short8*)vp;
    short8 v2  = *(const short8*)(vp + 1024);
    f32x16 s_cur = __builtin_amdgcn_mfma_f32_32x32x16_bf16(af0, bfi.v, zz, 0, 0, 0);

    // invariant at iter q: s_cur = S(q), v1/v2 = V(q), af1 = F(q+1), fp@q, vp@q
    #pragma unroll 2
    for (int q = 0; q < QW - 1; ++q) {
        // issue S(q+1) on the matrix pipe before consuming s_cur
        const f32x16 s_next =
            __builtin_amdgcn_mfma_f32_32x32x16_bf16(af1, bfi.v, zz, 0, 0, 0);
        if (q < QW - 2) af1 = *(const short8*)(fp + 1024);   // F(q+2)
        fp += 512;
        const short8 v1n = *(const short8*)(vp + 2048);       // V(q+1)
        const short8 v2n = *(const short8*)(vp + 2048 + 1024);
        vp += 2048;
        consume(s_cur, v1, v2);   // exp/pack/PV of q under S(q+1) latency
        s_cur = s_next; v1 = v1n; v2 = v2n;
    }
    consume(s_cur, v1, v2);       // last j-block

    // ---- epilogue: LDS transpose, then coalesced atomics ----
    #pragma unroll
    for (int r = 0; r < 16; ++r) {
        const int row = (r & 3) + 8 * (r >> 2) + 4 * half;  // i within subtile
        tile[row * 33 + il] = acc[r];
    }
    __builtin_amdgcn_s_waitcnt(0);  // lgkm drain within single wave (no barrier)
    #pragma unroll
    for (int cc = 0; cc < 11; ++cc) {
        const int c = 2 * cc + half;
        if (c < NC) {
            const float v = tile[il * 33 + c];
            atomicAdd(&outb[(size_t)c * NN + ibase + il], v);
        }
    }
}

extern "C" void kernel_launch(void* const* d_in, const int* in_sizes, int n_in,
                              void* d_out, int out_size, void* d_ws, size_t ws_size,
                              hipStream_t stream) {
    const float* cur = (const float*)d_in[0];  // cur_state  [2,21,96,96]
    const float* img = (const float*)d_in[1];  // input_image [2,3,96,96]
    float* out = (float*)d_out;
    unsigned char* ws = (unsigned char*)d_ws;  // needs ~1.77 MB

    prep_kernel<<<PREP_TASKS / BLK, BLK, 0, stream>>>(cur, img, ws, out);
    dim3 grid(NIT, G, NB);  // 288 x 24 x 2 = 13824 one-wave blocks
    perm_gauss_mfma<<<grid, MBLK, 0, stream>>>(img, ws, out);
}

// Round 8
// 91.983 us; speedup vs baseline: 1.0627x; 1.0627x over previous
//
#include <hip/hip_runtime.h>
#include <hip/hip_bf16.h>
#include <math.h>

// Bilateral Gaussian filter: out[b,c,i] = sum_j exp(-0.5|f_i-f_j|^2) * cur[b,c,j]
// f = [y/8, x/8, r/.5, g/.5, b/.5] (D=5). B=2, C=21, N=9216.
//
// Round 13: waves split J, LDS-combine, 4x fewer atomics.
//  R8/R11/R12 invariant: 44 MB @ 1.05 TB/s regardless of kernel structure ->
//  floor = memory-side atomic RMW ceiling (device atomics bypass the 8
//  non-coherent L2s; each G-pass writes the full output through to HBM;
//  WRITE_SIZE matches atomic-count*4B exactly in R7/R8).
//  Fix: same 13,824 waves (TLP unchanged), but a block's 4 waves now cover
//  4 j-ranges of the SAME 32-i subtile; acc tiles combined in LDS (one
//  barrier), one cooperative atomic pass per block. G'=6 passes: atomics
//  9.29M -> 2.32M, per-wave inner loop (QW=12, pipelined) byte-identical
//  to R12. Prep (2-node, zero-fold) unchanged.

#define HH 96
#define WW 96
#define NN (HH * WW)   // 9216
#define NB 2
#define NC 21

typedef __attribute__((ext_vector_type(8))) short short8;
typedef __attribute__((ext_vector_type(16))) float f32x16;

constexpr float INV_TA = 0.125f;  // 1/theta_alpha
constexpr float INV_TB = 2.0f;    // 1/theta_beta
constexpr float LOG2E  = 1.44269504088896340736f;

constexpr int BLK   = 256;           // block size (prep and main)
constexpr int ITILE = 32;            // i per block (all 4 waves share it)
constexpr int NIT   = NN / ITILE;    // 288
constexpr int NJB   = NN / 32;       // 288 j-blocks
constexpr int G2    = 6;             // atomic passes (j-groups of blocks)
constexpr int QW    = NJB / (G2*4);  // 12 j-blocks per wave (4 waves/block)

// ws layout: V [b][jblk(288)][m(2)][h(2)][c(32)] x 16B, then F [b][half][j] x 16B
constexpr size_t VG_BYTES = (size_t)NB * NJB * 128 * 16;  // 1,179,648
constexpr size_t FJA_OFF  = VG_BYTES;                     // + NB*2*NN*16 = 589,824

constexpr int NVU = NB * NJB * 128;        // 73728 V-pack tasks
constexpr int NFT = NB * NN;               // 18432 feature tasks
constexpr int NZ  = NB * NC * NN / 4;      // 96768 float4 zero units
constexpr int PREP_TASKS = NVU + NFT + NZ; // 188928 = 738*256

#if defined(__has_builtin)
#if __has_builtin(__builtin_amdgcn_exp2f)
#define EXP2F(x) __builtin_amdgcn_exp2f(x)
#endif
#endif
#ifndef EXP2F
#define EXP2F(x) exp2f(x)
#endif

__device__ __forceinline__ unsigned short bf16_rne(float f) {
    __hip_bfloat16 h = __float2bfloat16(f);
    unsigned short u; __builtin_memcpy(&u, &h, 2); return u;
}
__device__ __forceinline__ float bf16_f(unsigned short u) {
    __hip_bfloat16 h; __builtin_memcpy(&h, &u, 2); return __bfloat162float(h);
}
// pack two fp32 -> dword of two bf16 (round-up-bias trick; prep only)
__device__ __forceinline__ unsigned pk2(float a, float b) {
    const unsigned u0 = __float_as_uint(a) + 0x8000u;
    const unsigned u1 = __float_as_uint(b) + 0x8000u;
    return __builtin_amdgcn_perm(u1, u0, 0x07060302u);  // low=a, high=b
}
// packed RNE fp32x2 -> bf16x2 via HIP intrinsic (compiler emits v_cvt_pk)
__device__ __forceinline__ unsigned pkrn(float a, float b) {
    __hip_bfloat162 h = __float22bfloat162_rn(float2{a, b});  // x=lo, y=hi
    unsigned u; __builtin_memcpy(&u, &h, 4); return u;
}

// ---------------- prep: pack V, F_j fragments, zero out ----------------
__global__ __launch_bounds__(BLK)
void prep_kernel(const float* __restrict__ cur, const float* __restrict__ img,
                 unsigned char* __restrict__ ws, float* __restrict__ out) {
    const int t = blockIdx.x * BLK + threadIdx.x;
    if (t < NVU) {
        // V unit: t = ((b*288+jblk)*4 + m*2 + h)*32 + c -> 8 bf16 = V[j(k)][c]
        const int c    = t & 31;
        const int h    = (t >> 5) & 1;
        const int m    = (t >> 6) & 1;
        const int jw   = t >> 7;          // b*288 + jblk
        const int b    = jw / NJB;
        const int jblk = jw % NJB;
        // k-slot s=8h+t' -> physical j offset = swap bits2,3 of s:
        //   t'=0..3 -> jb+t', t'=4..7 -> jb+8+(t'&3)
        const int jb = jblk * 32 + m * 16 + 4 * h;
        float4 qa = {0, 0, 0, 0}, qb = {0, 0, 0, 0};
        if (c < NC) {
            const float* row = cur + ((size_t)b * NC + c) * NN;
            qa = *(const float4*)(row + jb);
            qb = *(const float4*)(row + jb + 8);
        }
        uint4 o;
        o.x = pk2(qa.x, qa.y); o.y = pk2(qa.z, qa.w);
        o.z = pk2(qb.x, qb.y); o.w = pk2(qb.z, qb.w);
        *(uint4*)(ws + (size_t)t * 16) = o;
    } else if (t < NVU + NFT) {
        const int tf = t - NVU;
        const int b = tf / NN;
        const int j = tf % NN;
        const float y = (float)(j / WW) * INV_TA;   // exact in bf16
        const float x = (float)(j % WW) * INV_TA;   // exact in bf16
        const float* ib = img + (size_t)b * 3 * NN;
        unsigned short ch[3], cl[3]; float cf[3];
        #pragma unroll
        for (int d = 0; d < 3; ++d) {
            const float c = ib[d * NN + j] * INV_TB;
            ch[d] = bf16_rne(c);
            const float chf = bf16_f(ch[d]);
            cl[d] = bf16_rne(c - chf);
            cf[d] = chf + bf16_f(cl[d]);
        }
        const float e = -0.5f * (y * y + x * x +
                                 cf[0] * cf[0] + cf[1] * cf[1] + cf[2] * cf[2]);
        const unsigned short eh = bf16_rne(e);
        const unsigned short el = bf16_rne(e - bf16_f(eh));
        const unsigned short yb = bf16_rne(y), xb = bf16_rne(x);
        const unsigned short one = 0x3F80;
        unsigned short* u0 = (unsigned short*)
            (ws + FJA_OFF + ((size_t)(b * 2 + 0) * NN + j) * 16);
        unsigned short* u1 = (unsigned short*)
            (ws + FJA_OFF + ((size_t)(b * 2 + 1) * NN + j) * 16);
        // A-frag slots 0-7:  [y, x, ch0,ch1,ch2, cl0,cl1,cl2]
        u0[0] = yb; u0[1] = xb; u0[2] = ch[0]; u0[3] = ch[1]; u0[4] = ch[2];
        u0[5] = cl[0]; u0[6] = cl[1]; u0[7] = cl[2];
        // A-frag slots 8-15: [ch0,ch1,ch2, ejh, ejl, 1, 1, 0]
        u1[0] = ch[0]; u1[1] = ch[1]; u1[2] = ch[2]; u1[3] = eh; u1[4] = el;
        u1[5] = one; u1[6] = one; u1[7] = 0;
    } else {
        ((float4*)out)[t - NVU - NFT] = float4{0.0f, 0.0f, 0.0f, 0.0f};
    }
}

// ---------------- main kernel: 4 waves split J, LDS-combine ----------------
__global__ __launch_bounds__(BLK)
void perm_gauss_mfma(const float* __restrict__ img,
                     const unsigned char* __restrict__ ws,
                     float* __restrict__ out) {
    __shared__ __align__(16) float tile[4 * 32 * 33];   // per-wave acc tiles
    const int tid  = threadIdx.x;
    const int lane = tid & 63;
    const int wave = tid >> 6;    // j-range selector (i shared by all waves)
    const int il   = lane & 31;
    const int half = lane >> 5;

    const int it = blockIdx.x, g = blockIdx.y, b = blockIdx.z;
    const int ibase = it * ITILE;
    const float* imgb = img + (size_t)b * 3 * NN;
    float* outb = out + (size_t)b * NC * NN;

    // ---- B-operand fragment: F_i for my column i, my k-half ----
    const int ig = ibase + il;
    const float y = (float)(ig / WW) * INV_TA;
    const float x = (float)(ig % WW) * INV_TA;
    unsigned short ch[3], cl[3]; float cf[3];
    #pragma unroll
    for (int d = 0; d < 3; ++d) {
        const float c = imgb[d * NN + ig] * INV_TB;
        ch[d] = bf16_rne(c);
        const float chf = bf16_f(ch[d]);
        cl[d] = bf16_rne(c - chf);
        cf[d] = chf + bf16_f(cl[d]);
    }
    const float e = -0.5f * (y * y + x * x +
                             cf[0] * cf[0] + cf[1] * cf[1] + cf[2] * cf[2]);
    const unsigned short eh = bf16_rne(e);
    const unsigned short el = bf16_rne(e - bf16_f(eh));
    const unsigned short one = 0x3F80;
    union { unsigned short u[8]; short8 v; } bfi;
    if (half == 0) {
        // B slots 0-7: [y, x, ch0,ch1,ch2, ch0,ch1,ch2]
        bfi.u[0] = bf16_rne(y); bfi.u[1] = bf16_rne(x);
        bfi.u[2] = ch[0]; bfi.u[3] = ch[1]; bfi.u[4] = ch[2];
        bfi.u[5] = ch[0]; bfi.u[6] = ch[1]; bfi.u[7] = ch[2];
    } else {
        // B slots 8-15: [cl0,cl1,cl2, 1, 1, eih, eil, 0]
        bfi.u[0] = cl[0]; bfi.u[1] = cl[1]; bfi.u[2] = cl[2];
        bfi.u[3] = one; bfi.u[4] = one; bfi.u[5] = eh; bfi.u[6] = el;
        bfi.u[7] = 0;
    }

    f32x16 acc, zz;
    #pragma unroll
    for (int r = 0; r < 16; ++r) { acc[r] = 0.0f; zz[r] = 0.0f; }

    // ---- stream this wave's j-range from L2-resident ws ----
    const int jb0 = (g * 4 + wave) * QW;
    const unsigned char* fp = ws + FJA_OFF +
        ((size_t)(b * 2 + half) * NN + (size_t)jb0 * 32 + il) * 16;
    const unsigned char* vp = ws +
        ((size_t)(b * NJB + jb0) * 128 + half * 32 + il) * 16;

    // exp/pack + PV for one j-block (consumes s, V1, V2)
    auto consume = [&](const f32x16& s, short8 V1, short8 V2) {
        float w[16];
        #pragma unroll
        for (int r = 0; r < 16; ++r) w[r] = EXP2F(s[r] * LOG2E);
        union { unsigned dw[4]; short8 v; } a1, a2;
        #pragma unroll
        for (int d = 0; d < 4; ++d) {
            a1.dw[d] = pkrn(w[2 * d],     w[2 * d + 1]);
            a2.dw[d] = pkrn(w[8 + 2 * d], w[9 + 2 * d]);
        }
        acc = __builtin_amdgcn_mfma_f32_32x32x16_bf16(a1.v, V1, acc, 0, 0, 0);
        acc = __builtin_amdgcn_mfma_f32_32x32x16_bf16(a2.v, V2, acc, 0, 0, 0);
    };

    // prologue: af for q=0,1; V for q=0; S for q=0 in flight
    short8 af0 = *(const short8*)fp;
    short8 af1 = *(const short8*)(fp + 512);
    short8 v1  = *(const short8*)vp;
    short8 v2  = *(const short8*)(vp + 1024);
    f32x16 s_cur = __builtin_amdgcn_mfma_f32_32x32x16_bf16(af0, bfi.v, zz, 0, 0, 0);

    // invariant at iter q: s_cur = S(q), v1/v2 = V(q), af1 = F(q+1), fp@q, vp@q
    #pragma unroll 2
    for (int q = 0; q < QW - 1; ++q) {
        // issue S(q+1) on the matrix pipe before consuming s_cur
        const f32x16 s_next =
            __builtin_amdgcn_mfma_f32_32x32x16_bf16(af1, bfi.v, zz, 0, 0, 0);
        if (q < QW - 2) af1 = *(const short8*)(fp + 1024);   // F(q+2)
        fp += 512;
        const short8 v1n = *(const short8*)(vp + 2048);       // V(q+1)
        const short8 v2n = *(const short8*)(vp + 2048 + 1024);
        vp += 2048;
        consume(s_cur, v1, v2);   // exp/pack/PV of q under S(q+1) latency
        s_cur = s_next; v1 = v1n; v2 = v2n;
    }
    consume(s_cur, v1, v2);       // last j-block

    // ---- epilogue: per-wave LDS transpose, combine 4 waves, one atomic pass
    float* mytile = tile + wave * (32 * 33);
    #pragma unroll
    for (int r = 0; r < 16; ++r) {
        const int row = (r & 3) + 8 * (r >> 2) + 4 * half;  // i within subtile
        mytile[row * 33 + il] = acc[r];
    }
    __syncthreads();
    // 256 threads cover 21 c x 32 i in 3 passes: c = cc*8 + tid/32, i = tid%32
    const int ci = tid >> 5;    // 0..7
    const int ii = tid & 31;
    #pragma unroll
    for (int cc = 0; cc < 3; ++cc) {
        const int c = cc * 8 + ci;
        if (c < NC) {
            const float v = tile[0 * 1056 + ii * 33 + c]
                          + tile[1 * 1056 + ii * 33 + c]
                          + tile[2 * 1056 + ii * 33 + c]
                          + tile[3 * 1056 + ii * 33 + c];
            atomicAdd(&outb[(size_t)c * NN + ibase + ii], v);
        }
    }
}

extern "C" void kernel_launch(void* const* d_in, const int* in_sizes, int n_in,
                              void* d_out, int out_size, void* d_ws, size_t ws_size,
                              hipStream_t stream) {
    const float* cur = (const float*)d_in[0];  // cur_state  [2,21,96,96]
    const float* img = (const float*)d_in[1];  // input_image [2,3,96,96]
    float* out = (float*)d_out;
    unsigned char* ws = (unsigned char*)d_ws;  // needs ~1.77 MB

    prep_kernel<<<PREP_TASKS / BLK, BLK, 0, stream>>>(cur, img, ws, out);
    dim3 grid(NIT, G2, NB);  // 288 x 6 x 2 = 3456 blocks, 4 waves each
    perm_gauss_mfma<<<grid, BLK, 0, stream>>>(img, ws, out);
}